// Round 2
// baseline (719.922 us; speedup 1.0000x reference)
//
#include <hip/hip_runtime.h>

#define BB 16
#define SS 2048
#define DD 128
#define SCALE 0.08838834764831845f  // 1/sqrt(128)

typedef __attribute__((ext_vector_type(8))) short bf16x8;
typedef __attribute__((ext_vector_type(4))) float f32x4;

__device__ __forceinline__ unsigned short f2bf(float f) {
    union { float f; unsigned int u; } v; v.f = f;
    unsigned int u = v.u;
    return (unsigned short)((u + 0x7fffu + ((u >> 16) & 1u)) >> 16);  // RNE
}

// ---- fused pre-pass: Q,K fp32->bf16 copies; V fp32 -> bf16 transposed [B][D][S] ----
__global__ __launch_bounds__(256) void prep_kernel(const float* __restrict__ Q,
                                                   const float* __restrict__ K,
                                                   const float* __restrict__ V,
                                                   unsigned short* __restrict__ Qb,
                                                   unsigned short* __restrict__ Kb,
                                                   unsigned short* __restrict__ Vt) {
    int bid = blockIdx.x;
    int tid = threadIdx.x;
    if (bid < 8192) {
        const float* src = (bid < 4096) ? Q : K;
        unsigned short* dst = (bid < 4096) ? Qb : Kb;
        int idx = ((bid & 4095) * 256 + tid) * 4;
        float4 f = *(const float4*)(src + idx);
        ushort4 o;
        o.x = f2bf(f.x); o.y = f2bf(f.y); o.z = f2bf(f.z); o.w = f2bf(f.w);
        *(ushort4*)(dst + idx) = o;
        return;
    }
    __shared__ unsigned short sT[64 * 132];
    int tb = bid - 8192;
    int b = tb >> 5;
    int s0 = (tb & 31) * 64;
#pragma unroll
    for (int rnd = 0; rnd < 8; ++rnd) {
        int slot = rnd * 256 + tid;
        int row = slot >> 5;        // 0..63 (s)
        int c4 = (slot & 31) * 4;   // 0..124 (d)
        float4 f = *(const float4*)(V + (size_t)(b * SS + s0 + row) * DD + c4);
        unsigned short* p = &sT[row * 132 + c4];
        p[0] = f2bf(f.x); p[1] = f2bf(f.y); p[2] = f2bf(f.z); p[3] = f2bf(f.w);
    }
    __syncthreads();
#pragma unroll
    for (int rnd = 0; rnd < 4; ++rnd) {
        int slot = rnd * 256 + tid;
        int d = slot >> 3;          // 0..127
        int k8 = (slot & 7) * 8;    // 0..56
        __align__(16) unsigned short tmp[8];
#pragma unroll
        for (int e = 0; e < 8; ++e) tmp[e] = sT[(k8 + e) * 132 + d];
        *(ushort4*)(Vt + (size_t)(b * DD + d) * SS + s0 + k8) = *(ushort4*)&tmp[0];
        *(ushort4*)(Vt + (size_t)(b * DD + d) * SS + s0 + k8 + 4) = *(ushort4*)&tmp[4];
    }
}

// ---- main fused attention: one block per (b, 32-row q tile); 1024 blocks, 3/CU ----
__global__ __launch_bounds__(256, 3) void attn_kernel(const unsigned short* __restrict__ Qb,
                                                      const unsigned short* __restrict__ Kb,
                                                      const unsigned short* __restrict__ Vt,
                                                      const int* __restrict__ mask,
                                                      float* __restrict__ outO,
                                                      float* __restrict__ outA) {
    // LDS: sQ 32x136 | sK 64x136 (sP 32x72 aliased) | sV 128x72 (sLpart aliased)
    __shared__ __align__(16) char smem[44544];
    unsigned short* sQ = (unsigned short*)smem;                  // 8704 B
    unsigned short* sK = (unsigned short*)(smem + 8704);         // 17408 B
    unsigned short* sP = sK;                                     // 4608 B alias (phase2 only, post-B3)
    unsigned short* sV = (unsigned short*)(smem + 8704 + 17408); // 18432 B
    float* sLpart = (float*)sV;                                  // 256 B alias (between phases)

    // XCD-aware swizzle: XCD x handles batches {2x, 2x+1}
    int bi = blockIdx.x;
    int slot = bi >> 3;
    int b = (bi & 7) * 2 + (slot >> 6);
    int qt = slot & 63;

    int tid = threadIdx.x;
    int wave = tid >> 6, lane = tid & 63, lo = lane & 15, hi = lane >> 4;
    const int r0 = (wave >> 1) * 16;  // wave's 16 q-rows
    const int c0 = (wave & 1) * 32;   // wave's 32 key-cols

    const unsigned short* KbB = Kb + (size_t)b * SS * DD;
    const unsigned short* VtB = Vt + (size_t)b * DD * SS;
    const int* maskB = mask + b * SS;

    // stage Q tile (32 x 128) once
    const unsigned short* Qbase = Qb + (size_t)(b * SS + qt * 32) * DD;
#pragma unroll
    for (int rnd = 0; rnd < 2; ++rnd) {
        int sl = rnd * 256 + tid;
        int row = sl >> 4, coff = (sl & 15) * 8;
        *(int4*)&sQ[row * 136 + coff] = *(const int4*)(Qbase + row * DD + coff);
    }

    // ---------- phase 1: row sums (register-accumulated) ----------
    int4 kreg[4];
#pragma unroll
    for (int rnd = 0; rnd < 4; ++rnd) {
        int sl = rnd * 256 + tid;
        int row = sl >> 4, coff = (sl & 15) * 8;
        kreg[rnd] = *(const int4*)(KbB + row * DD + coff);
    }
    float regsum[4] = {0.f, 0.f, 0.f, 0.f};
    for (int kt = 0; kt < 32; ++kt) {
        __syncthreads();
#pragma unroll
        for (int rnd = 0; rnd < 4; ++rnd) {
            int sl = rnd * 256 + tid;
            int row = sl >> 4, coff = (sl & 15) * 8;
            *(int4*)&sK[row * 136 + coff] = kreg[rnd];
        }
        float m0 = maskB[kt * 64 + c0 + lo] ? 1.f : 0.f;
        float m1 = maskB[kt * 64 + c0 + 16 + lo] ? 1.f : 0.f;
        if (kt < 31) {
#pragma unroll
            for (int rnd = 0; rnd < 4; ++rnd) {
                int sl = rnd * 256 + tid;
                int row = sl >> 4, coff = (sl & 15) * 8;
                kreg[rnd] = *(const int4*)(KbB + ((kt + 1) * 64 + row) * DD + coff);
            }
        }
        __syncthreads();
        f32x4 acc[2];
        acc[0] = (f32x4){0.f, 0.f, 0.f, 0.f};
        acc[1] = (f32x4){0.f, 0.f, 0.f, 0.f};
#pragma unroll
        for (int ks = 0; ks < 4; ++ks) {
            bf16x8 af = *(const bf16x8*)&sQ[(r0 + lo) * 136 + ks * 32 + hi * 8];
            bf16x8 bf0 = *(const bf16x8*)&sK[(c0 + lo) * 136 + ks * 32 + hi * 8];
            bf16x8 bf1 = *(const bf16x8*)&sK[(c0 + 16 + lo) * 136 + ks * 32 + hi * 8];
            acc[0] = __builtin_amdgcn_mfma_f32_16x16x32_bf16(af, bf0, acc[0], 0, 0, 0);
            acc[1] = __builtin_amdgcn_mfma_f32_16x16x32_bf16(af, bf1, acc[1], 0, 0, 0);
        }
#pragma unroll
        for (int r = 0; r < 4; ++r)
            regsum[r] += __expf(acc[0][r] * SCALE) * m0 + __expf(acc[1][r] * SCALE) * m1;
    }
    // one shfl reduction over the 16 lo-lanes
#pragma unroll
    for (int r = 0; r < 4; ++r) {
        float v = regsum[r];
        v += __shfl_xor(v, 1);
        v += __shfl_xor(v, 2);
        v += __shfl_xor(v, 4);
        v += __shfl_xor(v, 8);
        regsum[r] = v;
    }
    if (lo == 0) {
#pragma unroll
        for (int r = 0; r < 4; ++r) sLpart[(wave & 1) * 32 + r0 + hi * 4 + r] = regsum[r];
    }
    __syncthreads();
    float linv[4];
#pragma unroll
    for (int r = 0; r < 4; ++r) {
        int row = r0 + hi * 4 + r;
        linv[r] = 1.f / (sLpart[row] + sLpart[32 + row]);
    }
    // (top-of-loop barrier below orders the sV staging that clobbers sLpart)

    // ---------- phase 2: recompute S, write attn, accumulate O = P V ----------
    int4 kreg2[4], vreg[4];
#pragma unroll
    for (int rnd = 0; rnd < 4; ++rnd) {
        int sl = rnd * 256 + tid;
        int row = sl >> 4, coff = (sl & 15) * 8;
        kreg2[rnd] = *(const int4*)(KbB + row * DD + coff);
    }
#pragma unroll
    for (int rnd = 0; rnd < 4; ++rnd) {
        int sl = rnd * 256 + tid;
        int row = sl >> 3, koff = (sl & 7) * 8;
        vreg[rnd] = *(const int4*)(VtB + (size_t)row * SS + koff);
    }
    f32x4 oacc[2][2];
#pragma unroll
    for (int mi = 0; mi < 2; ++mi)
#pragma unroll
        for (int tj = 0; tj < 2; ++tj) oacc[mi][tj] = (f32x4){0.f, 0.f, 0.f, 0.f};
    const int dv0 = wave * 32;
    float* outArow = outA + (size_t)(b * SS + qt * 32) * SS;

    for (int kt = 0; kt < 32; ++kt) {
        __syncthreads();  // B1: prev iter's PV reads of sP/sV done (and sLpart read, kt=0)
#pragma unroll
        for (int rnd = 0; rnd < 4; ++rnd) {
            int sl = rnd * 256 + tid;
            int row = sl >> 4, coff = (sl & 15) * 8;
            *(int4*)&sK[row * 136 + coff] = kreg2[rnd];
        }
#pragma unroll
        for (int rnd = 0; rnd < 4; ++rnd) {
            int sl = rnd * 256 + tid;
            int row = sl >> 3, koff = (sl & 7) * 8;
            *(int4*)&sV[row * 72 + koff] = vreg[rnd];
        }
        float m0 = maskB[kt * 64 + c0 + lo] ? 1.f : 0.f;
        float m1 = maskB[kt * 64 + c0 + 16 + lo] ? 1.f : 0.f;
        if (kt < 31) {
#pragma unroll
            for (int rnd = 0; rnd < 4; ++rnd) {
                int sl = rnd * 256 + tid;
                int row = sl >> 4, coff = (sl & 15) * 8;
                kreg2[rnd] = *(const int4*)(KbB + ((kt + 1) * 64 + row) * DD + coff);
            }
#pragma unroll
            for (int rnd = 0; rnd < 4; ++rnd) {
                int sl = rnd * 256 + tid;
                int row = sl >> 3, koff = (sl & 7) * 8;
                vreg[rnd] = *(const int4*)(VtB + (size_t)row * SS + (kt + 1) * 64 + koff);
            }
        }
        __syncthreads();  // B2: staging visible
        f32x4 acc[2];
        acc[0] = (f32x4){0.f, 0.f, 0.f, 0.f};
        acc[1] = (f32x4){0.f, 0.f, 0.f, 0.f};
#pragma unroll
        for (int ks = 0; ks < 4; ++ks) {
            bf16x8 af = *(const bf16x8*)&sQ[(r0 + lo) * 136 + ks * 32 + hi * 8];
            bf16x8 bf0 = *(const bf16x8*)&sK[(c0 + lo) * 136 + ks * 32 + hi * 8];
            bf16x8 bf1 = *(const bf16x8*)&sK[(c0 + 16 + lo) * 136 + ks * 32 + hi * 8];
            acc[0] = __builtin_amdgcn_mfma_f32_16x16x32_bf16(af, bf0, acc[0], 0, 0, 0);
            acc[1] = __builtin_amdgcn_mfma_f32_16x16x32_bf16(af, bf1, acc[1], 0, 0, 0);
        }
        __syncthreads();  // B3: all waves done reading sK (sP aliases it)
#pragma unroll
        for (int jj = 0; jj < 2; ++jj) {
            float mj = jj ? m1 : m0;
#pragma unroll
            for (int r = 0; r < 4; ++r) {
                int row = r0 + hi * 4 + r;
                int col = c0 + jj * 16 + lo;
                float p = __expf(acc[jj][r] * SCALE) * mj * linv[r];
                outArow[(size_t)row * SS + kt * 64 + col] = p;
                sP[row * 72 + col] = f2bf(p);
            }
        }
        __syncthreads();  // B4: sP complete
#pragma unroll
        for (int ks = 0; ks < 2; ++ks) {
            bf16x8 pa[2], vb[2];
#pragma unroll
            for (int mi = 0; mi < 2; ++mi)
                pa[mi] = *(const bf16x8*)&sP[(mi * 16 + lo) * 72 + ks * 32 + hi * 8];
#pragma unroll
            for (int tj = 0; tj < 2; ++tj)
                vb[tj] = *(const bf16x8*)&sV[(dv0 + tj * 16 + lo) * 72 + ks * 32 + hi * 8];
#pragma unroll
            for (int mi = 0; mi < 2; ++mi)
#pragma unroll
                for (int tj = 0; tj < 2; ++tj)
                    oacc[mi][tj] = __builtin_amdgcn_mfma_f32_16x16x32_bf16(pa[mi], vb[tj], oacc[mi][tj], 0, 0, 0);
        }
    }

    // write O
    float* outOrow = outO + (size_t)(b * SS + qt * 32) * DD;
#pragma unroll
    for (int mi = 0; mi < 2; ++mi) {
#pragma unroll
        for (int tj = 0; tj < 2; ++tj) {
#pragma unroll
            for (int r = 0; r < 4; ++r) {
                int row = mi * 16 + hi * 4 + r;
                int dv = dv0 + tj * 16 + lo;
                outOrow[(size_t)row * DD + dv] = oacc[mi][tj][r];
            }
        }
    }
}

extern "C" void kernel_launch(void* const* d_in, const int* in_sizes, int n_in,
                              void* d_out, int out_size, void* d_ws, size_t ws_size,
                              hipStream_t stream) {
    const float* Q = (const float*)d_in[0];
    const float* K = (const float*)d_in[1];
    const float* V = (const float*)d_in[2];
    const int* mask = (const int*)d_in[3];

    float* outO = (float*)d_out;                          // [B,S,D]
    float* outA = outO + (size_t)BB * SS * DD;            // [B,S,S]

    unsigned short* Qb = (unsigned short*)d_ws;           // bf16 [B,S,D]
    unsigned short* Kb = Qb + (size_t)BB * SS * DD;       // bf16 [B,S,D]
    unsigned short* Vt = Kb + (size_t)BB * SS * DD;       // bf16 [B,D,S]

    prep_kernel<<<8192 + BB * (SS / 64), 256, 0, stream>>>(Q, K, V, Qb, Kb, Vt);
    attn_kernel<<<BB * (SS / 32), 256, 0, stream>>>(Qb, Kb, Vt, mask, outO, outA);
}